// Round 3
// baseline (545.252 us; speedup 1.0000x reference)
//
#include <hip/hip_runtime.h>
#include <stdint.h>

constexpr int SEQ = 1024;
constexpr int BSZ = 8;
constexpr int NHEAD = 16;
constexpr int DHEAD = 64;
constexpr int DMODEL = 1024;

using u16 = unsigned short;
using bf16x8 = __attribute__((ext_vector_type(8))) short;
using f32x4 = __attribute__((ext_vector_type(4))) float;

__device__ __forceinline__ float bf2f(u16 u) {
  union { unsigned int i; float f; } c; c.i = ((unsigned int)u) << 16; return c.f;
}
__device__ __forceinline__ u16 f2bf(float f) {
  union { float f; unsigned int i; } c; c.f = f;
  unsigned int x = c.i;
  return (u16)((x + 0x7FFFu + ((x >> 16) & 1u)) >> 16);
}
// async global->LDS, 16B per lane; LDS dest = wave-uniform base + lane*16
__device__ __forceinline__ void gload16(const void* g, void* l) {
  __builtin_amdgcn_global_load_lds((const __attribute__((address_space(1))) void*)g,
                                   (__attribute__((address_space(3))) void*)l, 16, 0, 0);
}
// load 8 consecutive f32, convert to bf16x8
__device__ __forceinline__ bf16x8 cvt8(const float* src) {
  f32x4 a = *(const f32x4*)src;
  f32x4 b = *(const f32x4*)(src + 4);
  bf16x8 o;
#pragma unroll
  for (int e = 0; e < 4; e++) { o[e] = (short)f2bf(a[e]); o[e + 4] = (short)f2bf(b[e]); }
  return o;
}

// ---------------- bf16-MFMA GEMM: C = A(MxK) @ BT(NxK)^T, 128x128 tile, BK=64
// A32: A operand is f32 (reg-staged + converted); else bf16 via global_load_lds.
// C32: C written as f32; else bf16.
template <int A32, int C32>
__global__ __launch_bounds__(256, 2) void gemm_bt(
    const void* __restrict__ Ap, int lda,
    const u16* __restrict__ BT, int ldb,
    void* __restrict__ Cp, int ldc, int K) {
  __shared__ __align__(16) u16 As[128 * 64];
  __shared__ __align__(16) u16 Bs[128 * 64];
  const int t = threadIdx.x;
  const int lane = t & 63;
  const int w = t >> 6, wr = w >> 1, wc = w & 1;
  const int l15 = lane & 15, l4 = lane >> 4;
  const int row0 = blockIdx.y * 128, col0 = blockIdx.x * 128;
  f32x4 acc[4][4] = {};
  for (int k0 = 0; k0 < K; k0 += 64) {
#pragma unroll
    for (int q = 0; q < 4; q++) {
      int u = q * 256 + t;
      int r = u >> 3, c8 = u & 7;
      int sc8 = c8 ^ (r & 7);               // pre-swizzled source -> swizzled LDS
      int ub = (q * 256 + (t & ~63)) * 8;   // wave-uniform LDS base (u16 elems)
      gload16(BT + (size_t)(col0 + r) * ldb + k0 + sc8 * 8, Bs + ub);
      if (A32) {
        const float* src = (const float*)Ap + (size_t)(row0 + r) * lda + k0 + sc8 * 8;
        *(bf16x8*)(As + (size_t)u * 8) = cvt8(src);
      } else {
        gload16((const u16*)Ap + (size_t)(row0 + r) * lda + k0 + sc8 * 8, As + ub);
      }
    }
    __syncthreads();
#pragma unroll
    for (int kk = 0; kk < 2; kk++) {
      bf16x8 av[4], bv[4];
#pragma unroll
      for (int f = 0; f < 4; f++) {
        int ar = wr * 64 + f * 16 + l15;
        int br = wc * 64 + f * 16 + l15;
        int kb = kk * 32 + l4 * 8;
        av[f] = *(const bf16x8*)((const char*)As + (((ar * 64 + kb) * 2) ^ ((ar & 7) << 4)));
        bv[f] = *(const bf16x8*)((const char*)Bs + (((br * 64 + kb) * 2) ^ ((br & 7) << 4)));
      }
#pragma unroll
      for (int fr = 0; fr < 4; fr++)
#pragma unroll
        for (int fc = 0; fc < 4; fc++)
          acc[fr][fc] = __builtin_amdgcn_mfma_f32_16x16x32_bf16(av[fr], bv[fc], acc[fr][fc], 0, 0, 0);
    }
    __syncthreads();
  }
#pragma unroll
  for (int fr = 0; fr < 4; fr++)
#pragma unroll
    for (int fc = 0; fc < 4; fc++) {
      int col = col0 + wc * 64 + fc * 16 + l15;
#pragma unroll
      for (int r = 0; r < 4; r++) {
        int row = row0 + wr * 64 + fr * 16 + l4 * 4 + r;
        if (C32) ((float*)Cp)[(size_t)row * ldc + col] = acc[fr][fc][r];
        else     ((u16*)Cp)[(size_t)row * ldc + col] = f2bf(acc[fr][fc][r]);
      }
    }
}

// ---------------- BD = (Q+rr_bias) @ R^T for one (b,n) slice, K=64, rel_shift scatter epilogue
__global__ __launch_bounds__(256, 2) void bd_gemm(
    const u16* __restrict__ Qb, const u16* __restrict__ Rk,
    const float* __restrict__ rrb, u16* __restrict__ BDS, int z0) {
  __shared__ __align__(16) u16 As[128 * 64];
  __shared__ __align__(16) u16 Bs[128 * 64];
  const int t = threadIdx.x;
  const int lane = t & 63;
  const int w = t >> 6, wr = w >> 1, wc = w & 1;
  const int l15 = lane & 15, l4 = lane >> 4;
  const int m0 = blockIdx.x * 128, i0 = blockIdx.y * 128;
  const int z = z0 + blockIdx.z, b = z >> 4, n = z & 15;
#pragma unroll
  for (int q = 0; q < 4; q++) {
    int u = q * 256 + t;
    int r = u >> 3, c8 = u & 7;
    int sc8 = c8 ^ (r & 7);
    int ub = (q * 256 + (t & ~63)) * 8;
    gload16(Rk + (size_t)(m0 + r) * DMODEL + n * DHEAD + sc8 * 8, Bs + ub);
    // A: reg-staged Q (bf16) + rrb (f32), same linear LDS image as gload16
    bf16x8 qv = *(const bf16x8*)(Qb + ((size_t)(i0 + r) * BSZ + b) * DMODEL + n * DHEAD + sc8 * 8);
    f32x4 b0 = *(const f32x4*)(rrb + n * DHEAD + sc8 * 8);
    f32x4 b1 = *(const f32x4*)(rrb + n * DHEAD + sc8 * 8 + 4);
    bf16x8 o;
#pragma unroll
    for (int e = 0; e < 4; e++) {
      o[e] = (short)f2bf(bf2f((u16)qv[e]) + b0[e]);
      o[e + 4] = (short)f2bf(bf2f((u16)qv[e + 4]) + b1[e]);
    }
    *(bf16x8*)(As + (size_t)u * 8) = o;
  }
  __syncthreads();
  f32x4 acc[4][4] = {};
#pragma unroll
  for (int kk = 0; kk < 2; kk++) {
    bf16x8 av[4], bv[4];
#pragma unroll
    for (int f = 0; f < 4; f++) {
      int ar = wr * 64 + f * 16 + l15;
      int br = wc * 64 + f * 16 + l15;
      int kb = kk * 32 + l4 * 8;
      av[f] = *(const bf16x8*)((const char*)As + (((ar * 64 + kb) * 2) ^ ((ar & 7) << 4)));
      bv[f] = *(const bf16x8*)((const char*)Bs + (((br * 64 + kb) * 2) ^ ((br & 7) << 4)));
    }
#pragma unroll
    for (int fr = 0; fr < 4; fr++)
#pragma unroll
      for (int fc = 0; fc < 4; fc++)
        acc[fr][fc] = __builtin_amdgcn_mfma_f32_16x16x32_bf16(av[fr], bv[fc], acc[fr][fc], 0, 0, 0);
  }
  // rel_shift scatter: D[i,m] -> BDS[i, m+i-(S-1)] if m+i>=S-1 else BDS[i-1, m+i+1]
  u16* bz = BDS + (size_t)blockIdx.z * SEQ * SEQ;
#pragma unroll
  for (int fr = 0; fr < 4; fr++)
#pragma unroll
    for (int fc = 0; fc < 4; fc++)
#pragma unroll
      for (int r = 0; r < 4; r++) {
        int i = i0 + wr * 64 + fr * 16 + l4 * 4 + r;
        int m = m0 + wc * 64 + fc * 16 + l15;
        u16 v = f2bf(acc[fr][fc][r]);
        int j1 = m + i - (SEQ - 1);
        if (j1 >= 0) bz[(size_t)i * SEQ + j1] = v;
        else if (i > 0) bz[(size_t)(i - 1) * SEQ + (m + i + 1)] = v;
      }
}

// ---------------- flash attention per (q-tile 64, slice): AC MFMA + BDS + online softmax + PV
__global__ __launch_bounds__(256, 2) void flash_attn(
    const u16* __restrict__ Qb, const u16* __restrict__ Kb,
    const u16* __restrict__ VT, const float* __restrict__ rwb,
    const u16* __restrict__ BDS, u16* __restrict__ AV, int z0) {
  __shared__ __align__(16) u16 Qs[64 * 64];
  __shared__ __align__(16) u16 Ks[64 * 64];
  __shared__ __align__(16) u16 Vs[64 * 64];   // V^T tile: rows d, cols j
  __shared__ __align__(16) u16 Bds[64 * 64];
  __shared__ __align__(16) u16 Ps[4][16 * 64];
  const int t = threadIdx.x;
  const int lane = t & 63;
  const int w = t >> 6;
  const int l15 = lane & 15, l4 = lane >> 4;
  const int i0 = blockIdx.x * 64;
  const int s = blockIdx.y;
  const int z = z0 + s, b = z >> 4, n = z & 15;
  const float scale = 0.125f;  // 1/sqrt(64)

#pragma unroll
  for (int q = 0; q < 2; q++) {  // stage Q once, + rwb on the fly
    int u = q * 256 + t;
    int r = u >> 3, c8 = u & 7;
    int sc8 = c8 ^ (r & 7);
    bf16x8 qv = *(const bf16x8*)(Qb + ((size_t)(i0 + r) * BSZ + b) * DMODEL + n * DHEAD + sc8 * 8);
    f32x4 b0 = *(const f32x4*)(rwb + n * DHEAD + sc8 * 8);
    f32x4 b1 = *(const f32x4*)(rwb + n * DHEAD + sc8 * 8 + 4);
    bf16x8 o;
#pragma unroll
    for (int e = 0; e < 4; e++) {
      o[e] = (short)f2bf(bf2f((u16)qv[e]) + b0[e]);
      o[e + 4] = (short)f2bf(bf2f((u16)qv[e + 4]) + b1[e]);
    }
    *(bf16x8*)(Qs + (size_t)u * 8) = o;
  }
  f32x4 O[4] = {};
  float M[4], L[4];
#pragma unroll
  for (int r = 0; r < 4; r++) { M[r] = -1e30f; L[r] = 0.f; }
  const u16* bds_n = BDS + (size_t)s * SEQ * SEQ;

  for (int j0 = 0; j0 < SEQ; j0 += 64) {
    if (j0) __syncthreads();  // protect LDS from previous iteration's readers
#pragma unroll
    for (int q = 0; q < 2; q++) {
      int u = q * 256 + t;
      int r = u >> 3, c8 = u & 7;
      int sc8 = c8 ^ (r & 7);
      int ub = (q * 256 + (t & ~63)) * 8;
      gload16(Kb + ((size_t)(j0 + r) * BSZ + b) * DMODEL + n * DHEAD + sc8 * 8, Ks + ub);
      gload16(VT + ((size_t)(b * NHEAD + n) * DHEAD + r) * SEQ + j0 + sc8 * 8, Vs + ub);
      gload16(bds_n + (size_t)(i0 + r) * SEQ + j0 + sc8 * 8, Bds + ub);
    }
    __syncthreads();
    // QK^T: wave w owns q rows [w*16, w*16+16)
    f32x4 sacc[4] = {};
#pragma unroll
    for (int kk = 0; kk < 2; kk++) {
      int kb = kk * 32 + l4 * 8;
      int qr = w * 16 + l15;
      bf16x8 a = *(const bf16x8*)((const char*)Qs + (((qr * 64 + kb) * 2) ^ ((qr & 7) << 4)));
#pragma unroll
      for (int fc = 0; fc < 4; fc++) {
        int kr = fc * 16 + l15;
        bf16x8 bb = *(const bf16x8*)((const char*)Ks + (((kr * 64 + kb) * 2) ^ ((kr & 7) << 4)));
        sacc[fc] = __builtin_amdgcn_mfma_f32_16x16x32_bf16(a, bb, sacc[fc], 0, 0, 0);
      }
    }
    // + BD (shifted; diag j=i+1 is the zero-pad artifact), scale, online softmax
    float p[4][4];
#pragma unroll
    for (int r = 0; r < 4; r++) {
      int lrow = w * 16 + l4 * 4 + r;  // local q row in 64-tile
      int iq = i0 + lrow;              // global i
      float tm = -1e30f;
#pragma unroll
      for (int fc = 0; fc < 4; fc++) {
        int bc = fc * 16 + l15;
        int jj = j0 + bc;
        float bd = 0.f;
        if (jj != iq + 1)
          bd = bf2f(*(const u16*)((const char*)Bds + (((lrow * 64 + bc) * 2) ^ ((lrow & 7) << 4))));
        float v = (sacc[fc][r] + bd) * scale;
        p[fc][r] = v;
        tm = fmaxf(tm, v);
      }
      for (int mk = 1; mk < 16; mk <<= 1) tm = fmaxf(tm, __shfl_xor(tm, mk, 16));
      float Mn = fmaxf(M[r], tm);
      float alpha = __expf(M[r] - Mn);
      float rsum = 0.f;
#pragma unroll
      for (int fc = 0; fc < 4; fc++) {
        float e = __expf(p[fc][r] - Mn);
        p[fc][r] = e;
        rsum += e;
      }
      for (int mk = 1; mk < 16; mk <<= 1) rsum += __shfl_xor(rsum, mk, 16);
      L[r] = L[r] * alpha + rsum;
      M[r] = Mn;
#pragma unroll
      for (int fd = 0; fd < 4; fd++) O[fd][r] *= alpha;
    }
    // P -> LDS (per-wave region, bf16, swizzled)
    u16* ps = (u16*)Ps[w];
#pragma unroll
    for (int fc = 0; fc < 4; fc++)
#pragma unroll
      for (int r = 0; r < 4; r++) {
        int pr = l4 * 4 + r, pc = fc * 16 + l15;
        *(u16*)((char*)ps + (((pr * 64 + pc) * 2) ^ ((pr & 7) << 4))) = f2bf(p[fc][r]);
      }
    // PV: O[16q x 64d] += P[16q x 64j] @ V[64j x 64d] (V^T staged -> contiguous B-frags)
#pragma unroll
    for (int kk = 0; kk < 2; kk++) {
      int kb = kk * 32 + l4 * 8;
      int pr = l15;
      bf16x8 a = *(const bf16x8*)((const char*)ps + (((pr * 64 + kb) * 2) ^ ((pr & 7) << 4)));
#pragma unroll
      for (int fd = 0; fd < 4; fd++) {
        int vr = fd * 16 + l15;
        bf16x8 bb = *(const bf16x8*)((const char*)Vs + (((vr * 64 + kb) * 2) ^ ((vr & 7) << 4)));
        O[fd] = __builtin_amdgcn_mfma_f32_16x16x32_bf16(a, bb, O[fd], 0, 0, 0);
      }
    }
  }
#pragma unroll
  for (int fd = 0; fd < 4; fd++)
#pragma unroll
    for (int r = 0; r < 4; r++) {
      int iq = i0 + w * 16 + l4 * 4 + r;
      int d = fd * 16 + l15;
      AV[((size_t)iq * BSZ + b) * DMODEL + n * DHEAD + d] = f2bf(O[fd][r] / L[r]);
    }
}

// ---------------- weight transpose + f32->bf16: out(CxR, bf16) = in(RxC, f32)^T
__global__ void wtrans(const float* __restrict__ in, u16* __restrict__ out, int R, int C) {
  __shared__ unsigned int lds[64][65];
  const int t = threadIdx.x;
  const int c0 = blockIdx.x * 64, r0 = blockIdx.y * 64;
#pragma unroll
  for (int p = 0; p < 2; p++) {
    int u = p * 256 + t;
    int r = u >> 3, c8 = u & 7;
    const float* src = in + (size_t)(r0 + r) * C + c0 + c8 * 8;
    f32x4 v0 = *(const f32x4*)src;
    f32x4 v1 = *(const f32x4*)(src + 4);
#pragma unroll
    for (int e = 0; e < 4; e++) {
      lds[r][c8 * 8 + e] = f2bf(v0[e]);
      lds[r][c8 * 8 + 4 + e] = f2bf(v1[e]);
    }
  }
  __syncthreads();
#pragma unroll
  for (int p = 0; p < 2; p++) {
    int u = p * 256 + t;
    int r = u >> 3, c8 = u & 7;
    bf16x8 v;
#pragma unroll
    for (int e = 0; e < 8; e++) v[e] = (short)lds[c8 * 8 + e][r];
    *(bf16x8*)(out + (size_t)(c0 + r) * R + r0 + c8 * 8) = v;
  }
}

// ---------------- V^T builder: VT[((b*NH+n)*64+d)*SEQ + s] = Vb[(s*BSZ+b)*1024 + n*64 + d]
__global__ void vtrans(const u16* __restrict__ Vb, u16* __restrict__ VT) {
  __shared__ unsigned int lds[64][65];
  const int t = threadIdx.x;
  const int s0 = blockIdx.x * 64, n = blockIdx.y, b = blockIdx.z;
#pragma unroll
  for (int p = 0; p < 2; p++) {
    int u = p * 256 + t;
    int r = u >> 3, c8 = u & 7;  // r = s offset, c8*8 = d offset
    const u16* src = Vb + ((size_t)(s0 + r) * BSZ + b) * DMODEL + n * DHEAD + c8 * 8;
    bf16x8 v = *(const bf16x8*)src;
#pragma unroll
    for (int e = 0; e < 8; e++) lds[r][c8 * 8 + e] = (u16)v[e];
  }
  __syncthreads();
#pragma unroll
  for (int p = 0; p < 2; p++) {
    int u = p * 256 + t;
    int r = u >> 3, c8 = u & 7;  // r = d row, c8*8 = s offset
    bf16x8 v;
#pragma unroll
    for (int e = 0; e < 8; e++) v[e] = (short)lds[c8 * 8 + e][r];
    *(bf16x8*)(VT + ((size_t)(b * NHEAD + n) * DHEAD + r) * SEQ + s0 + c8 * 8) = v;
  }
}

// ---------------- residual + LayerNorm (f32, in-place on out), one 256-thread block per row
__global__ void ln_kernel(const float* __restrict__ hidden,
                          const float* __restrict__ gamma, const float* __restrict__ beta,
                          float* __restrict__ out) {
  __shared__ float wsum[4];
  __shared__ float wvar[4];
  const int row = blockIdx.x;
  const int t = threadIdx.x;
  f32x4 hv = *(const f32x4*)(hidden + (size_t)row * DMODEL + t * 4);
  f32x4 ov = *(const f32x4*)(out + (size_t)row * DMODEL + t * 4);
  float xs[4], sum = 0.f;
#pragma unroll
  for (int e = 0; e < 4; e++) { xs[e] = hv[e] + ov[e]; sum += xs[e]; }
  for (int mk = 1; mk < 64; mk <<= 1) sum += __shfl_xor(sum, mk, 64);
  if ((t & 63) == 0) wsum[t >> 6] = sum;
  __syncthreads();
  float mu = (wsum[0] + wsum[1] + wsum[2] + wsum[3]) * (1.f / DMODEL);
  float var = 0.f;
#pragma unroll
  for (int e = 0; e < 4; e++) { float d = xs[e] - mu; var += d * d; }
  for (int mk = 1; mk < 64; mk <<= 1) var += __shfl_xor(var, mk, 64);
  if ((t & 63) == 0) wvar[t >> 6] = var;
  __syncthreads();
  float rstd = rsqrtf((wvar[0] + wvar[1] + wvar[2] + wvar[3]) * (1.f / DMODEL) + 1e-5f);
  f32x4 res;
#pragma unroll
  for (int e = 0; e < 4; e++) {
    int c = t * 4 + e;
    res[e] = (xs[e] - mu) * rstd * gamma[c] + beta[c];
  }
  *(f32x4*)(out + (size_t)row * DMODEL + t * 4) = res;
}

extern "C" void kernel_launch(void* const* d_in, const int* in_sizes, int n_in,
                              void* d_out, int out_size, void* d_ws, size_t ws_size,
                              hipStream_t stream) {
  const float* hidden = (const float*)d_in[0];
  const float* relpos = (const float*)d_in[1];
  const float* enc    = (const float*)d_in[2];
  const float* W_q    = (const float*)d_in[3];
  const float* W_kv   = (const float*)d_in[4];
  const float* W_r    = (const float*)d_in[5];
  const float* W_o    = (const float*)d_in[6];
  const float* rwb    = (const float*)d_in[7];
  const float* rrb    = (const float*)d_in[8];
  const float* gamma  = (const float*)d_in[9];
  const float* beta   = (const float*)d_in[10];
  float* out = (float*)d_out;

  char* ws = (char*)d_ws;
  size_t off = 0;
  auto alloc = [&](size_t bytes) { char* p = ws + off; off += (bytes + 255) & ~(size_t)255; return p; };
  const size_t MB = 1024 * 1024;
  // persistent region (bf16 internals): 68 MB
  u16* WOT = (u16*)alloc(2 * MB);    // W_o^T
  u16* Qb  = (u16*)alloc(16 * MB);   // plain Q heads (no bias)
  u16* Kb  = (u16*)alloc(16 * MB);   // K heads
  u16* VT  = (u16*)alloc(16 * MB);   // V transposed per (b,n): [d][s]
  u16* AV  = (u16*)alloc(16 * MB);   // attn output; ALSO V staging buffer (dead after vtrans)
  u16* Rh  = (u16*)alloc(2 * MB);    // rel_pos_emb @ W_r
  u16* Vb  = AV;                     // alias
  // arena: transposed W_q/W_kv/W_r live here until projections finish, then BDS reuses it.
  size_t arena_off = off;
  u16* WQT  = (u16*)alloc(2 * MB);
  u16* WKVT = (u16*)alloc(4 * MB);
  u16* WRT  = (u16*)alloc(2 * MB);
  u16* BDS = (u16*)(ws + arena_off);
  size_t per_slice = (size_t)SEQ * SEQ * 2;  // 2 MB per (b,head)
  long long avail = (long long)ws_size - (long long)arena_off;
  int nz = (avail > 0) ? (int)(avail / (long long)per_slice) : 1;
  if (nz < 1) nz = 1;
  if (nz > BSZ * NHEAD) nz = BSZ * NHEAD;

  dim3 blk(256);
  wtrans<<<dim3(16, 16), blk, 0, stream>>>(W_q, WQT, 1024, 1024);
  wtrans<<<dim3(32, 16), blk, 0, stream>>>(W_kv, WKVT, 1024, 2048);
  wtrans<<<dim3(16, 16), blk, 0, stream>>>(W_r, WRT, 1024, 1024);
  wtrans<<<dim3(16, 16), blk, 0, stream>>>(W_o, WOT, 1024, 1024);

  gemm_bt<1, 0><<<dim3(8, 64), blk, 0, stream>>>(hidden, 1024, WQT, 1024, Qb, 1024, 1024);
  gemm_bt<1, 0><<<dim3(8, 64), blk, 0, stream>>>(enc, 1024, WKVT, 1024, Kb, 1024, 1024);
  gemm_bt<1, 0><<<dim3(8, 64), blk, 0, stream>>>(enc, 1024, WKVT + (size_t)1024 * 1024, 1024, Vb, 1024, 1024);
  gemm_bt<1, 0><<<dim3(8, 8), blk, 0, stream>>>(relpos, 1024, WRT, 1024, Rh, 1024, 1024);
  vtrans<<<dim3(16, NHEAD, BSZ), blk, 0, stream>>>(Vb, VT);

  for (int z0 = 0; z0 < BSZ * NHEAD; z0 += nz) {
    int nzc = (nz < BSZ * NHEAD - z0) ? nz : (BSZ * NHEAD - z0);
    bd_gemm<<<dim3(8, 8, nzc), blk, 0, stream>>>(Qb, Rh, rrb, BDS, z0);
    flash_attn<<<dim3(16, nzc), blk, 0, stream>>>(Qb, Kb, VT, rwb, BDS, AV, z0);
  }

  gemm_bt<0, 1><<<dim3(8, 64), blk, 0, stream>>>(AV, 1024, WOT, 1024, out, 1024, 1024);
  ln_kernel<<<dim3(8192), blk, 0, stream>>>(hidden, gamma, beta, out);
}